// Round 1
// baseline (367.975 us; speedup 1.0000x reference)
//
#include <hip/hip_runtime.h>

constexpr int BATCH = 1000000;
constexpr int NBINS = 37;
constexpr int TPB = 256;
constexpr int TILE_ROWS = 256;
constexpr int TILE_FLOATS = TILE_ROWS * NBINS;   // 9472 floats = 37888 B
constexpr float NEG_BIG = -1e30f;
constexpr float LOGCLAMP = -100.0f;

__global__ __launch_bounds__(TPB, 4)
void adviser_loss_kernel(const float* __restrict__ preds,
                         const float* __restrict__ labels,
                         const float* __restrict__ weights,
                         const int* __restrict__ obj_classes,
                         float* __restrict__ out)
{
    __shared__ float tile[TILE_FLOATS];
    __shared__ float cls_sum[3];

    const int tid  = threadIdx.x;
    const int row0 = blockIdx.x * TILE_ROWS;
    const int nrows = min(TILE_ROWS, BATCH - row0);
    const int nvec  = (nrows * NBINS) >> 2;   // nrows%4==0 always (256 or 64 tail)

    if (tid < 3) cls_sum[tid] = 0.0f;

    // ---- stage preds tile (coalesced float4; tile base is 16B-aligned) ----
    {
        const float4* g = (const float4*)(preds + (size_t)row0 * NBINS);
        float4* l = (float4*)tile;
        for (int i = tid; i < nvec; i += TPB) l[i] = g[i];
    }
    __syncthreads();

    const bool valid = (tid < nrows);
    int c = 0;
    float w = 0.0f;
    if (valid) {
        c = obj_classes[row0 + tid];
        w = weights[c];
    }
    const int s = 13 * c;                 // slice start: 0 / 13 / 26
    const int L = (c == 2) ? 11 : 13;     // slice length: 13 / 13 / 11
    const int base = tid * NBINS + s;

    float pv[13];
    #pragma unroll
    for (int j = 0; j < 13; ++j)
        pv[j] = (valid && j < L) ? tile[base + j] : NEG_BIG;

    float m = NEG_BIG;
    #pragma unroll
    for (int j = 0; j < 13; ++j) m = fmaxf(m, pv[j]);
    float Z = 0.0f;
    #pragma unroll
    for (int j = 0; j < 13; ++j) Z += __expf(pv[j] - m);
    const float logZ = __logf(Z);

    __syncthreads();   // everyone done reading preds tile

    // ---- stage labels tile into the SAME buffer ----
    {
        const float4* g = (const float4*)(labels + (size_t)row0 * NBINS);
        float4* l = (float4*)tile;
        for (int i = tid; i < nvec; i += TPB) l[i] = g[i];
    }
    __syncthreads();

    float lv[13];
    #pragma unroll
    for (int j = 0; j < 13; ++j)
        lv[j] = (valid && j < L) ? tile[base + j] : NEG_BIG;

    float mt = NEG_BIG;
    #pragma unroll
    for (int j = 0; j < 13; ++j) mt = fmaxf(mt, lv[j]);
    float Zt = 0.0f;
    #pragma unroll
    for (int j = 0; j < 13; ++j) Zt += __expf(lv[j] - mt);
    const float rcpZt = 1.0f / Zt;

    // ---- fused BCE over the slice (inactive j contribute exactly 0) ----
    float acc = 0.0f;
    #pragma unroll
    for (int j = 0; j < 13; ++j) {
        const float logp = pv[j] - m - logZ;          // <= 0 mathematically
        const float p    = fminf(__expf(logp), 1.0f); // guard log1p(-p) NaN
        const float t    = __expf(lv[j] - mt) * rcpZt;
        const float ca   = fmaxf(logp, LOGCLAMP);
        const float cb   = fmaxf(log1pf(-p), LOGCLAMP);
        acc -= t * ca + (1.0f - t) * cb;
    }
    const float per_sample = valid ? acc * w : 0.0f;

    // ---- reduce: 3 class sums, wave-shuffle then LDS then global atomics ----
    float v0 = (c == 0) ? per_sample : 0.0f;
    float v1 = (c == 1) ? per_sample : 0.0f;
    float v2 = (c == 2) ? per_sample : 0.0f;
    #pragma unroll
    for (int off = 32; off > 0; off >>= 1) {
        v0 += __shfl_down(v0, off, 64);
        v1 += __shfl_down(v1, off, 64);
        v2 += __shfl_down(v2, off, 64);
    }
    if ((tid & 63) == 0) {
        atomicAdd(&cls_sum[0], v0);
        atomicAdd(&cls_sum[1], v1);
        atomicAdd(&cls_sum[2], v2);
    }
    __syncthreads();
    if (tid < 3) atomicAdd(&out[1 + tid], cls_sum[tid]);
    if (tid == 0)
        atomicAdd(&out[0], (cls_sum[0] + cls_sum[1] + cls_sum[2]) * (1.0f / (float)BATCH));
}

extern "C" void kernel_launch(void* const* d_in, const int* in_sizes, int n_in,
                              void* d_out, int out_size, void* d_ws, size_t ws_size,
                              hipStream_t stream) {
    const float* preds   = (const float*)d_in[0];
    const float* labels  = (const float*)d_in[1];
    const float* weights = (const float*)d_in[2];
    const int*   obj     = (const int*)d_in[3];
    float* out = (float*)d_out;

    hipMemsetAsync(out, 0, (size_t)out_size * sizeof(float), stream);
    const int grid = (BATCH + TILE_ROWS - 1) / TILE_ROWS;
    adviser_loss_kernel<<<grid, TPB, 0, stream>>>(preds, labels, weights, obj, out);
}